// Round 1
// baseline (728.354 us; speedup 1.0000x reference)
//
#include <hip/hip_runtime.h>
#include <math.h>

#define N_NODES 10000
#define D_IN 1000
#define D0 256
#define D1 128
#define NEG_SLOPE 0.2f

// ---------------- CSR build ----------------

__global__ void count_kernel(const int* __restrict__ idx, int E, int n, int* __restrict__ counts) {
  int k = blockIdx.x * blockDim.x + threadIdx.x;
  int tot = E + n;
  if (k >= tot) return;
  int dst = (k < E) ? idx[E + k] : (k - E);   // self-loops appended
  atomicAdd(&counts[dst], 1);
}

__global__ void scan_kernel(const int* __restrict__ counts, int* __restrict__ offsets,
                            int* __restrict__ cursors, int n) {
  __shared__ int tsum[1024];
  int tid = threadIdx.x;
  int per = (n + 1023) / 1024;
  int start = tid * per;
  int end = start + per; if (end > n) end = n;
  int s = 0;
  for (int i = start; i < end; i++) s += counts[i];
  tsum[tid] = s;
  __syncthreads();
  for (int off = 1; off < 1024; off <<= 1) {
    int v = (tid >= off) ? tsum[tid - off] : 0;
    __syncthreads();
    if (tid >= off) tsum[tid] += v;
    __syncthreads();
  }
  int run = (tid == 0) ? 0 : tsum[tid - 1];
  for (int i = start; i < end; i++) {
    offsets[i] = run; cursors[i] = run;
    run += counts[i];
  }
  if (tid == 1023) offsets[n] = tsum[1023];
}

__global__ void scatter_kernel(const int* __restrict__ idx, int E, int n,
                               int* __restrict__ cursors, int* __restrict__ srcs) {
  int k = blockIdx.x * blockDim.x + threadIdx.x;
  int tot = E + n;
  if (k >= tot) return;
  int src, dst;
  if (k < E) { src = idx[k]; dst = idx[E + k]; }
  else       { src = k - E;  dst = src; }
  int pos = atomicAdd(&cursors[dst], 1);
  srcs[pos] = src;
}

// ---------------- fp32 GEMM: C[M,N] = A[M,K] @ W[K,N] + b[N] ----------------
// 64x64 tile, BK=16, 256 threads, 4x4 outputs/thread. Fully guarded (M,N,K arbitrary).

#define TS 64
#define KS 16

__launch_bounds__(256)
__global__ void gemm_bias(const float* __restrict__ A, const float* __restrict__ W,
                          const float* __restrict__ b, float* __restrict__ C,
                          int M, int K, int N) {
  __shared__ float As[KS][TS + 4];   // transposed A tile: As[k][m]
  __shared__ float Bs[KS][TS + 4];
  const int t  = threadIdx.x;
  const int tx = t & 15, ty = t >> 4;
  const int bm = blockIdx.y * TS, bn = blockIdx.x * TS;

  float acc[4][4] = {};

  for (int k0 = 0; k0 < K; k0 += KS) {
    // A tile: 64 rows x 16 k-cols; each thread loads 4 consecutive k's of one row
    {
      int row  = t >> 2;
      int col4 = (t & 3) * 4;
      int gr   = bm + row;
      #pragma unroll
      for (int j = 0; j < 4; j++) {
        int gk = k0 + col4 + j;
        As[col4 + j][row] = (gr < M && gk < K) ? A[(long)gr * K + gk] : 0.f;
      }
      // B tile: 16 k-rows x 64 cols; each thread loads 4 consecutive cols of one k
      int brow = t >> 4;
      int bcol = (t & 15) * 4;
      int gk2  = k0 + brow;
      #pragma unroll
      for (int j = 0; j < 4; j++) {
        int gc = bn + bcol + j;
        Bs[brow][bcol + j] = (gk2 < K && gc < N) ? W[(long)gk2 * N + gc] : 0.f;
      }
    }
    __syncthreads();
    #pragma unroll
    for (int k = 0; k < KS; k++) {
      float a[4], bb[4];
      #pragma unroll
      for (int i = 0; i < 4; i++) a[i]  = As[k][ty * 4 + i];
      #pragma unroll
      for (int j = 0; j < 4; j++) bb[j] = Bs[k][tx * 4 + j];
      #pragma unroll
      for (int i = 0; i < 4; i++)
        #pragma unroll
        for (int j = 0; j < 4; j++)
          acc[i][j] = fmaf(a[i], bb[j], acc[i][j]);
    }
    __syncthreads();
  }

  #pragma unroll
  for (int i = 0; i < 4; i++) {
    int gr = bm + ty * 4 + i;
    if (gr >= M) continue;
    #pragma unroll
    for (int j = 0; j < 4; j++) {
      int gc = bn + tx * 4 + j;
      if (gc < N) C[(long)gr * N + gc] = acc[i][j] + b[gc];
    }
  }
}

// ---------------- fused GATv2 edge phase (per-dst-node block) ----------------
// For node v: e_k = leakyrelu(xl[u_k]+xr[v]) . att over incoming edges,
// online softmax over chunks of 64 edges, then out[v] = sum alpha_k * xl[u_k] + bias.

template<int D>
__launch_bounds__(D)
__global__ void gat_kernel(const float* __restrict__ xl, const float* __restrict__ xr,
                           const float* __restrict__ att, const float* __restrict__ bias,
                           const int* __restrict__ offsets, const int* __restrict__ srcs,
                           float* __restrict__ out) {
  constexpr int WAVES = D / 64;
  constexpr int EPL   = D / 64;   // floats per lane in the dot phase
  const int v    = blockIdx.x;
  const int tid  = threadIdx.x;
  const int lane = tid & 63;
  const int wave = tid >> 6;

  __shared__ float xr_s[D];
  __shared__ float att_s[D];
  __shared__ float e_s[64];
  __shared__ int   src_s[64];
  __shared__ float bc[3];   // [0]=scale, [1]=running max, [2]=running sum

  xr_s[tid]  = xr[(size_t)v * D + tid];
  att_s[tid] = att[tid];
  if (tid == 0) { bc[1] = -INFINITY; bc[2] = 0.f; }
  const int beg = offsets[v], end = offsets[v + 1];
  float acc = 0.f;
  __syncthreads();

  for (int cbeg = beg; cbeg < end; cbeg += 64) {
    const int c = min(64, end - cbeg);

    // Phase A: per-edge logits, one wave per edge, lanes cover D elems
    for (int k = wave; k < c; k += WAVES) {
      const int u = srcs[cbeg + k];
      float p = 0.f;
      if constexpr (EPL == 2) {
        const float2 xv = ((const float2*)(xl + (size_t)u * D))[lane];
        const int d0 = lane * 2;
        float t0 = xv.x + xr_s[d0];     t0 = t0 > 0.f ? t0 : NEG_SLOPE * t0;
        float t1 = xv.y + xr_s[d0 + 1]; t1 = t1 > 0.f ? t1 : NEG_SLOPE * t1;
        p = t0 * att_s[d0] + t1 * att_s[d0 + 1];
      } else {
        const float4 xv = ((const float4*)(xl + (size_t)u * D))[lane];
        const int d0 = lane * 4;
        float t0 = xv.x + xr_s[d0];     t0 = t0 > 0.f ? t0 : NEG_SLOPE * t0;
        float t1 = xv.y + xr_s[d0 + 1]; t1 = t1 > 0.f ? t1 : NEG_SLOPE * t1;
        float t2 = xv.z + xr_s[d0 + 2]; t2 = t2 > 0.f ? t2 : NEG_SLOPE * t2;
        float t3 = xv.w + xr_s[d0 + 3]; t3 = t3 > 0.f ? t3 : NEG_SLOPE * t3;
        p = t0 * att_s[d0] + t1 * att_s[d0 + 1] + t2 * att_s[d0 + 2] + t3 * att_s[d0 + 3];
      }
      #pragma unroll
      for (int off = 32; off > 0; off >>= 1) p += __shfl_xor(p, off);
      if (lane == 0) { e_s[k] = p; src_s[k] = u; }
    }
    __syncthreads();

    // Phase B: chunk softmax merge (wave 0)
    if (wave == 0) {
      float e  = (lane < c) ? e_s[lane] : -INFINITY;
      float cm = e;
      #pragma unroll
      for (int off = 32; off > 0; off >>= 1) cm = fmaxf(cm, __shfl_xor(cm, off));
      const float m_old = bc[1];
      const float m_new = fmaxf(m_old, cm);
      float p = (lane < c) ? __expf(e - m_new) : 0.f;
      if (lane < c) e_s[lane] = p;
      #pragma unroll
      for (int off = 32; off > 0; off >>= 1) p += __shfl_xor(p, off);
      if (lane == 0) {
        const float scale = __expf(m_old - m_new);
        bc[0] = scale;
        bc[1] = m_new;
        bc[2] = bc[2] * scale + p;
      }
    }
    __syncthreads();

    // Phase C: rescale + aggregate
    const float scale = bc[0];
    acc *= scale;
    for (int k = 0; k < c; k++) {
      acc = fmaf(e_s[k], xl[(size_t)src_s[k] * D + tid], acc);
    }
    __syncthreads();
  }

  out[(size_t)v * D + tid] = acc / bc[2] + bias[tid];
}

// ---------------- launch ----------------

extern "C" void kernel_launch(void* const* d_in, const int* in_sizes, int n_in,
                              void* d_out, int out_size, void* d_ws, size_t ws_size,
                              hipStream_t stream) {
  const float* x     = (const float*)d_in[0];
  const int*   eidx  = (const int*)d_in[1];
  const float* Wpi   = (const float*)d_in[2];
  const float* bpi   = (const float*)d_in[3];
  const float* Wl1   = (const float*)d_in[4];
  const float* bl1   = (const float*)d_in[5];
  const float* Wr1   = (const float*)d_in[6];
  const float* br1   = (const float*)d_in[7];
  const float* att1  = (const float*)d_in[8];
  const float* bias1 = (const float*)d_in[9];
  const float* Wl2   = (const float*)d_in[10];
  const float* bl2   = (const float*)d_in[11];
  const float* Wr2   = (const float*)d_in[12];
  const float* br2   = (const float*)d_in[13];
  const float* att2  = (const float*)d_in[14];
  const float* bias2 = (const float*)d_in[15];
  const float* Wpo   = (const float*)d_in[16];
  const float* bpo   = (const float*)d_in[17];

  const int E    = in_sizes[1] / 2;
  const int n    = N_NODES;
  const int Etot = E + n;

  float* out_xhat = (float*)d_out;
  float* out_z    = (float*)d_out + (size_t)N_NODES * D_IN;

  // workspace carve-up (256B aligned regions)
  char* wp = (char*)d_ws;
  auto alloc = [&](size_t bytes) { char* p = wp; wp += (bytes + 255) & ~(size_t)255; return p; };
  int*   counts  = (int*)alloc((size_t)n * 4);
  int*   offsets = (int*)alloc((size_t)(n + 1) * 4);
  int*   cursors = (int*)alloc((size_t)n * 4);
  int*   srcs    = (int*)alloc((size_t)Etot * 4);
  float* h       = (float*)alloc((size_t)n * D0 * 4);  // reused as xl2
  float* xl1     = (float*)alloc((size_t)n * D1 * 4);  // xl1+xr1 contiguous, reused as xr2
  float* xr1     = (float*)alloc((size_t)n * D1 * 4);
  float* dbuf    = (float*)alloc((size_t)n * D0 * 4);
  float* xl2 = h;
  float* xr2 = xl1;   // spans xl1+xr1 (each n*D1*4 is 256B-multiple, so contiguous)

  hipMemsetAsync(counts, 0, (size_t)n * 4, stream);
  const int tb = 256;
  count_kernel<<<(Etot + tb - 1) / tb, tb, 0, stream>>>(eidx, E, n, counts);
  scan_kernel<<<1, 1024, 0, stream>>>(counts, offsets, cursors, n);
  scatter_kernel<<<(Etot + tb - 1) / tb, tb, 0, stream>>>(eidx, E, n, cursors, srcs);

  // h = x @ Wpi + bpi
  gemm_bias<<<dim3((D0 + 63) / 64, (n + 63) / 64), 256, 0, stream>>>(x, Wpi, bpi, h, n, D_IN, D0);
  // xl1 / xr1
  gemm_bias<<<dim3((D1 + 63) / 64, (n + 63) / 64), 256, 0, stream>>>(h, Wl1, bl1, xl1, n, D0, D1);
  gemm_bias<<<dim3((D1 + 63) / 64, (n + 63) / 64), 256, 0, stream>>>(h, Wr1, br1, xr1, n, D0, D1);
  // z = GAT1(...)  -> second output region
  gat_kernel<D1><<<n, D1, 0, stream>>>(xl1, xr1, att1, bias1, offsets, srcs, out_z);
  // xl2 / xr2 from z
  gemm_bias<<<dim3((D0 + 63) / 64, (n + 63) / 64), 256, 0, stream>>>(out_z, Wl2, bl2, xl2, n, D1, D0);
  gemm_bias<<<dim3((D0 + 63) / 64, (n + 63) / 64), 256, 0, stream>>>(out_z, Wr2, br2, xr2, n, D1, D0);
  // d = GAT2(...)
  gat_kernel<D0><<<n, D0, 0, stream>>>(xl2, xr2, att2, bias2, offsets, srcs, dbuf);
  // x_hat = d @ Wpo + bpo
  gemm_bias<<<dim3((D_IN + 63) / 64, (n + 63) / 64), 256, 0, stream>>>(dbuf, Wpo, bpo, out_xhat, n, D0, D_IN);
}

// Round 3
// 420.569 us; speedup vs baseline: 1.7318x; 1.7318x over previous
//
#include <hip/hip_runtime.h>
#include <math.h>

#define N_NODES 10000
#define MPAD    10112   // 79 * 128
#define D_IN    1000
#define KPAD_IN 1024
#define D0      256
#define D1      128
#define NPAD_OUT 1024
#define NEG_SLOPE 0.2f

typedef __attribute__((ext_vector_type(8))) short short8;
typedef __attribute__((ext_vector_type(4))) float f32x4;

__device__ __forceinline__ ushort f2bf(float f) {
  union { float f; unsigned u; } c; c.f = f;
  unsigned r = c.u + 0x7FFF + ((c.u >> 16) & 1);   // RNE
  return (ushort)(r >> 16);
}

// ---------------- CSR build ----------------

__global__ void count_kernel(const int* __restrict__ idx, int E, int n, int* __restrict__ counts) {
  int k = blockIdx.x * blockDim.x + threadIdx.x;
  int tot = E + n;
  if (k >= tot) return;
  int dst = (k < E) ? idx[E + k] : (k - E);   // self-loops appended
  atomicAdd(&counts[dst], 1);
}

__global__ void scan_kernel(const int* __restrict__ counts, int* __restrict__ offsets,
                            int* __restrict__ cursors, int n) {
  __shared__ int tsum[1024];
  int tid = threadIdx.x;
  int per = (n + 1023) / 1024;
  int start = tid * per;
  int end = start + per; if (end > n) end = n;
  int s = 0;
  for (int i = start; i < end; i++) s += counts[i];
  tsum[tid] = s;
  __syncthreads();
  for (int off = 1; off < 1024; off <<= 1) {
    int v = (tid >= off) ? tsum[tid - off] : 0;
    __syncthreads();
    if (tid >= off) tsum[tid] += v;
    __syncthreads();
  }
  int run = (tid == 0) ? 0 : tsum[tid - 1];
  for (int i = start; i < end; i++) {
    offsets[i] = run; cursors[i] = run;
    run += counts[i];
  }
  if (tid == 1023) offsets[n] = tsum[1023];
}

__global__ void scatter_kernel(const int* __restrict__ idx, int E, int n,
                               int* __restrict__ cursors, int* __restrict__ srcs) {
  int k = blockIdx.x * blockDim.x + threadIdx.x;
  int tot = E + n;
  if (k >= tot) return;
  int src, dst;
  if (k < E) { src = idx[k]; dst = idx[E + k]; }
  else       { src = k - E;  dst = src; }
  int pos = atomicAdd(&cursors[dst], 1);
  srcs[pos] = src;
}

// ---------------- input / weight prep ----------------

// xb[r][k], r<MPAD, k<KPAD_IN: bf16(x) zero-padded
__global__ void conv_x_kernel(const float* __restrict__ x, ushort* __restrict__ xb) {
  int idx = blockIdx.x * blockDim.x + threadIdx.x;
  int r = idx >> 10, k = idx & 1023;
  float v = (r < N_NODES && k < D_IN) ? x[(size_t)r * D_IN + k] : 0.f;
  xb[idx] = f2bf(v);
}

// Wt[(n_off+n)*Kpad + k] = bf16(W[k*ldsrc + n]) with zero padding
__global__ void wprep_kernel(const float* __restrict__ W, ushort* __restrict__ Wt,
                             int K_src, int N_src, int ldsrc, int Kpad, int N_dst,
                             int n_off, int total) {
  int idx = blockIdx.x * blockDim.x + threadIdx.x;
  if (idx >= total) return;
  int n = idx / Kpad, k = idx - n * Kpad;
  float v = (k < K_src && n < N_src) ? W[(size_t)k * ldsrc + n] : 0.f;
  Wt[(size_t)(n_off + n) * Kpad + k] = f2bf(v);
}

__global__ void bprep_kernel(const float* __restrict__ bl1, const float* __restrict__ br1,
                             const float* __restrict__ bl2, const float* __restrict__ br2,
                             float* __restrict__ bcat1, float* __restrict__ bcat2) {
  int i = threadIdx.x;
  if (i < 128)      bcat1[i] = bl1[i];
  else if (i < 256) bcat1[i] = br1[i - 128];
  else if (i < 512) bcat2[i - 256] = bl2[i - 256];
  else              bcat2[i - 256] = br2[i - 512];
}

// ---------------- bf16 MFMA GEMM ----------------
// C[M,N] = A[M,K](bf16, lda) @ Bt[N,K](bf16, ldb)^T + bias
// 128x128 tile, BK=32, 4 waves (2x2), 16x16x32 MFMA, global_load_lds staging.

template<bool BF16_OUT>
__launch_bounds__(256)
__global__ void gemm_mfma(const ushort* __restrict__ A, int lda,
                          const ushort* __restrict__ Bt, int ldb,
                          const float* __restrict__ bias,
                          float* __restrict__ Cf, ushort* __restrict__ Cb, int ldc,
                          int M_valid, int N_valid, int K) {
  constexpr int BK = 32;
  __shared__ ushort As[128 * BK];
  __shared__ ushort Bs[128 * BK];
  const int tid  = threadIdx.x;
  const int lane = tid & 63, wave = tid >> 6;
  const int wr = wave >> 1, wc = wave & 1;
  const int bm = blockIdx.y * 128, bn = blockIdx.x * 128;
  const int r16 = lane & 15, kb = lane >> 4;

  f32x4 acc[4][4] = {};

  const int srow = tid >> 2;
  const int scol = (tid & 3) * 8;    // ushort elems (16B)
  const ushort* Ag0 = A  + (size_t)(bm + srow) * lda + scol;
  const ushort* Ag1 = A  + (size_t)(bm + 64 + srow) * lda + scol;
  const ushort* Bg0 = Bt + (size_t)(bn + srow) * ldb + scol;
  const ushort* Bg1 = Bt + (size_t)(bn + 64 + srow) * ldb + scol;

  for (int k0 = 0; k0 < K; k0 += BK) {
    __builtin_amdgcn_global_load_lds((const __attribute__((address_space(1))) void*)(Ag0 + k0),
                                     (__attribute__((address_space(3))) void*)(As + tid * 8), 16, 0, 0);
    __builtin_amdgcn_global_load_lds((const __attribute__((address_space(1))) void*)(Ag1 + k0),
                                     (__attribute__((address_space(3))) void*)(As + 2048 + tid * 8), 16, 0, 0);
    __builtin_amdgcn_global_load_lds((const __attribute__((address_space(1))) void*)(Bg0 + k0),
                                     (__attribute__((address_space(3))) void*)(Bs + tid * 8), 16, 0, 0);
    __builtin_amdgcn_global_load_lds((const __attribute__((address_space(1))) void*)(Bg1 + k0),
                                     (__attribute__((address_space(3))) void*)(Bs + 2048 + tid * 8), 16, 0, 0);
    __syncthreads();

    short8 af[4], bfr[4];
    #pragma unroll
    for (int mi = 0; mi < 4; mi++)
      af[mi] = *(const short8*)(As + ((wr * 64 + mi * 16 + r16) * BK + kb * 8));
    #pragma unroll
    for (int ni = 0; ni < 4; ni++)
      bfr[ni] = *(const short8*)(Bs + ((wc * 64 + ni * 16 + r16) * BK + kb * 8));
    #pragma unroll
    for (int mi = 0; mi < 4; mi++)
      #pragma unroll
      for (int ni = 0; ni < 4; ni++)
        acc[mi][ni] = __builtin_amdgcn_mfma_f32_16x16x32_bf16(af[mi], bfr[ni], acc[mi][ni], 0, 0, 0);
    __syncthreads();
  }

  #pragma unroll
  for (int mi = 0; mi < 4; mi++) {
    const int row = bm + wr * 64 + mi * 16 + (lane >> 4) * 4;
    #pragma unroll
    for (int ni = 0; ni < 4; ni++) {
      const int col = bn + wc * 64 + ni * 16 + r16;
      const float bv = (col < N_valid) ? bias[col] : 0.f;
      #pragma unroll
      for (int r = 0; r < 4; r++) {
        const int gr = row + r;
        const float val = acc[mi][ni][r] + bv;
        if constexpr (BF16_OUT) {
          Cb[(size_t)gr * ldc + col] = f2bf(gr < M_valid ? val : 0.f);
        } else {
          if (gr < M_valid && col < N_valid) Cf[(size_t)gr * ldc + col] = val;
        }
      }
    }
  }
}

// ---------------- fused GATv2 edge phase (per-dst-node block) ----------------

template<int D>
__launch_bounds__(D)
__global__ void gat_kernel(const float* __restrict__ xl, const float* __restrict__ xr, int ldx,
                           const float* __restrict__ att, const float* __restrict__ bias,
                           const int* __restrict__ offsets, const int* __restrict__ srcs,
                           float* __restrict__ out_f32, ushort* __restrict__ out_bf16,
                           int n_valid) {
  constexpr int WAVES = D / 64;
  constexpr int EPL   = D / 64;
  const int v    = blockIdx.x;
  const int tid  = threadIdx.x;
  const int lane = tid & 63;
  const int wave = tid >> 6;

  if (v >= n_valid) {               // pad rows -> zero bf16 row
    if (out_bf16) out_bf16[(size_t)v * D + tid] = 0;
    return;
  }

  __shared__ float xr_s[D];
  __shared__ float att_s[D];
  __shared__ float e_s[64];
  __shared__ int   src_s[64];
  __shared__ float bc[3];   // [0]=scale, [1]=running max, [2]=running sum

  xr_s[tid]  = xr[(size_t)v * ldx + tid];
  att_s[tid] = att[tid];
  if (tid == 0) { bc[1] = -INFINITY; bc[2] = 0.f; }
  const int beg = offsets[v], end = offsets[v + 1];
  float acc = 0.f;
  __syncthreads();

  for (int cbeg = beg; cbeg < end; cbeg += 64) {
    const int c = min(64, end - cbeg);

    // Phase A: per-edge logits, one wave per edge
    for (int k = wave; k < c; k += WAVES) {
      const int u = srcs[cbeg + k];
      float p = 0.f;
      if constexpr (EPL == 2) {
        const float2 xv = ((const float2*)(xl + (size_t)u * ldx))[lane];
        const int d0 = lane * 2;
        float t0 = xv.x + xr_s[d0];     t0 = t0 > 0.f ? t0 : NEG_SLOPE * t0;
        float t1 = xv.y + xr_s[d0 + 1]; t1 = t1 > 0.f ? t1 : NEG_SLOPE * t1;
        p = t0 * att_s[d0] + t1 * att_s[d0 + 1];
      } else {
        const float4 xv = ((const float4*)(xl + (size_t)u * ldx))[lane];
        const int d0 = lane * 4;
        float t0 = xv.x + xr_s[d0];     t0 = t0 > 0.f ? t0 : NEG_SLOPE * t0;
        float t1 = xv.y + xr_s[d0 + 1]; t1 = t1 > 0.f ? t1 : NEG_SLOPE * t1;
        float t2 = xv.z + xr_s[d0 + 2]; t2 = t2 > 0.f ? t2 : NEG_SLOPE * t2;
        float t3 = xv.w + xr_s[d0 + 3]; t3 = t3 > 0.f ? t3 : NEG_SLOPE * t3;
        p = t0 * att_s[d0] + t1 * att_s[d0 + 1] + t2 * att_s[d0 + 2] + t3 * att_s[d0 + 3];
      }
      #pragma unroll
      for (int off = 32; off > 0; off >>= 1) p += __shfl_xor(p, off);
      if (lane == 0) { e_s[k] = p; src_s[k] = u; }
    }
    __syncthreads();

    // Phase B: chunk softmax merge (wave 0)
    if (wave == 0) {
      float e  = (lane < c) ? e_s[lane] : -INFINITY;
      float cm = e;
      #pragma unroll
      for (int off = 32; off > 0; off >>= 1) cm = fmaxf(cm, __shfl_xor(cm, off));
      const float m_old = bc[1];
      const float m_new = fmaxf(m_old, cm);
      float p = (lane < c) ? __expf(e - m_new) : 0.f;
      if (lane < c) e_s[lane] = p;
      #pragma unroll
      for (int off = 32; off > 0; off >>= 1) p += __shfl_xor(p, off);
      if (lane == 0) {
        const float scale = __expf(m_old - m_new);
        bc[0] = scale;
        bc[1] = m_new;
        bc[2] = bc[2] * scale + p;
      }
    }
    __syncthreads();

    // Phase C: rescale + aggregate
    const float scale = bc[0];
    acc *= scale;
    for (int k = 0; k < c; k++) {
      acc = fmaf(e_s[k], xl[(size_t)src_s[k] * ldx + tid], acc);
    }
    __syncthreads();
  }

  const float val = acc / bc[2] + bias[tid];
  if (out_f32)  out_f32[(size_t)v * D + tid] = val;
  if (out_bf16) out_bf16[(size_t)v * D + tid] = f2bf(val);
}

// ---------------- launch ----------------

extern "C" void kernel_launch(void* const* d_in, const int* in_sizes, int n_in,
                              void* d_out, int out_size, void* d_ws, size_t ws_size,
                              hipStream_t stream) {
  const float* x     = (const float*)d_in[0];
  const int*   eidx  = (const int*)d_in[1];
  const float* Wpi   = (const float*)d_in[2];
  const float* bpi   = (const float*)d_in[3];
  const float* Wl1   = (const float*)d_in[4];
  const float* bl1   = (const float*)d_in[5];
  const float* Wr1   = (const float*)d_in[6];
  const float* br1   = (const float*)d_in[7];
  const float* att1  = (const float*)d_in[8];
  const float* bias1 = (const float*)d_in[9];
  const float* Wl2   = (const float*)d_in[10];
  const float* bl2   = (const float*)d_in[11];
  const float* Wr2   = (const float*)d_in[12];
  const float* br2   = (const float*)d_in[13];
  const float* att2  = (const float*)d_in[14];
  const float* bias2 = (const float*)d_in[15];
  const float* Wpo   = (const float*)d_in[16];
  const float* bpo   = (const float*)d_in[17];

  const int E    = in_sizes[1] / 2;
  const int n    = N_NODES;
  const int Etot = E + n;

  float* out_xhat = (float*)d_out;
  float* out_z    = (float*)d_out + (size_t)N_NODES * D_IN;

  // workspace carve-up
  char* wp = (char*)d_ws;
  auto alloc = [&](size_t bytes) { char* p = wp; wp += (bytes + 255) & ~(size_t)255; return p; };
  ushort* regionA = (ushort*)alloc((size_t)MPAD * KPAD_IN * 2);   // xb -> xlr1 -> xlr2
  ushort* hb_db   = (ushort*)alloc((size_t)MPAD * D0 * 2);        // hb then db
  ushort* zb      = (ushort*)alloc((size_t)MPAD * D1 * 2);
  int* counts  = (int*)alloc((size_t)n * 4);
  int* offsets = (int*)alloc((size_t)(n + 1) * 4);
  int* cursors = (int*)alloc((size_t)n * 4);
  int* srcs    = (int*)alloc((size_t)Etot * 4);
  ushort* Wpi_t = (ushort*)alloc((size_t)256 * 1024 * 2);
  ushort* W1cat = (ushort*)alloc((size_t)256 * 256 * 2);
  ushort* W2cat = (ushort*)alloc((size_t)512 * 128 * 2);
  ushort* Wpo_t = (ushort*)alloc((size_t)1024 * 256 * 2);
  float*  bcat1 = (float*)alloc(256 * 4);
  float*  bcat2 = (float*)alloc(512 * 4);

  ushort* xb   = regionA;
  float*  xlr1 = (float*)regionA;
  float*  xlr2 = (float*)regionA;
  ushort* hb   = hb_db;
  ushort* db   = hb_db;

  // CSR
  hipMemsetAsync(counts, 0, (size_t)n * 4, stream);
  const int tb = 256;
  count_kernel<<<(Etot + tb - 1) / tb, tb, 0, stream>>>(eidx, E, n, counts);
  scan_kernel<<<1, 1024, 0, stream>>>(counts, offsets, cursors, n);
  scatter_kernel<<<(Etot + tb - 1) / tb, tb, 0, stream>>>(eidx, E, n, cursors, srcs);

  // prep
  conv_x_kernel<<<(MPAD * KPAD_IN) / 256, 256, 0, stream>>>(x, xb);
  wprep_kernel<<<(256 * 1024) / 256, 256, 0, stream>>>(Wpi, Wpi_t, 1000, 256, 256, 1024, 256, 0, 256 * 1024);
  wprep_kernel<<<(128 * 256) / 256, 256, 0, stream>>>(Wl1, W1cat, 256, 128, 128, 256, 128, 0, 128 * 256);
  wprep_kernel<<<(128 * 256) / 256, 256, 0, stream>>>(Wr1, W1cat, 256, 128, 128, 256, 128, 128, 128 * 256);
  wprep_kernel<<<(256 * 128) / 256, 256, 0, stream>>>(Wl2, W2cat, 128, 256, 256, 128, 256, 0, 256 * 128);
  wprep_kernel<<<(256 * 128) / 256, 256, 0, stream>>>(Wr2, W2cat, 128, 256, 256, 128, 256, 256, 256 * 128);
  wprep_kernel<<<(1024 * 256) / 256, 256, 0, stream>>>(Wpo, Wpo_t, 256, 1000, 1000, 256, 1024, 0, 1024 * 256);
  bprep_kernel<<<1, 768, 0, stream>>>(bl1, br1, bl2, br2, bcat1, bcat2);

  // h = x @ Wpi + bpi  (bf16 out, padded)
  gemm_mfma<true><<<dim3(D0 / 128, MPAD / 128), 256, 0, stream>>>(
      xb, KPAD_IN, Wpi_t, KPAD_IN, bpi, nullptr, hb, D0, N_NODES, D0, KPAD_IN);
  // [xl1|xr1] = h @ [Wl1|Wr1] + [bl1|br1]  (f32 out, ld=256)
  gemm_mfma<false><<<dim3(256 / 128, MPAD / 128), 256, 0, stream>>>(
      hb, D0, W1cat, D0, bcat1, xlr1, nullptr, 256, N_NODES, 256, D0);
  // z = GAT1 -> out_z (f32) + zb (bf16 padded)
  gat_kernel<D1><<<MPAD, D1, 0, stream>>>(xlr1, xlr1 + D1, 256, att1, bias1,
                                          offsets, srcs, out_z, zb, N_NODES);
  // [xl2|xr2] = z @ [Wl2|Wr2] + [bl2|br2]  (f32 out, ld=512)
  gemm_mfma<false><<<dim3(512 / 128, MPAD / 128), 256, 0, stream>>>(
      zb, D1, W2cat, D1, bcat2, xlr2, nullptr, 512, N_NODES, 512, D1);
  // d = GAT2 -> db (bf16 padded)
  gat_kernel<D0><<<MPAD, D0, 0, stream>>>(xlr2, xlr2 + D0, 512, att2, bias2,
                                          offsets, srcs, nullptr, db, N_NODES);
  // x_hat = d @ Wpo + bpo  (f32 out, guarded to 1000 cols)
  gemm_mfma<false><<<dim3(NPAD_OUT / 128, MPAD / 128), 256, 0, stream>>>(
      db, D0, Wpo_t, D0, bpo, out_xhat, nullptr, D_IN, N_NODES, D_IN, D0);
}